// Round 5
// baseline (164.644 us; speedup 1.0000x reference)
//
#include <hip/hip_runtime.h>
#include <math.h>

#define NSITES 100000
#define NYEARS 20
#define HDIM 64
#define WSTR 72   // LDS weight row stride (bf16 elems); 144B, 16B-aligned
#define SPB 128   // sites per block (4 waves x 2 chains x 16 sites)

typedef __bf16 bf16x8 __attribute__((ext_vector_type(8)));
typedef float f32x4 __attribute__((ext_vector_type(4)));

__device__ __forceinline__ float sigmoidf_(float x) { return 1.0f / (1.0f + __expf(-x)); }
// fast elu: __expf(x)-1 (error ~1e-7, far below tolerance; result is bf16-truncated anyway)
__device__ __forceinline__ float eluf_(float x) { return x > 0.0f ? x : __expf(x) - 1.0f; }

__device__ __forceinline__ unsigned pack2_(float a, float b) {
    union { __bf16 h; unsigned short u; } x, y;
    x.h = (__bf16)a; y.h = (__bf16)b;
    return ((unsigned)y.u << 16) | (unsigned)x.u;
}

// load 8 consecutive f32 (32B-aligned) -> bf16x8
__device__ __forceinline__ bf16x8 cvt8_(const float* p) {
    float4 a = ((const float4*)p)[0];
    float4 b = ((const float4*)p)[1];
    bf16x8 r;
    r[0] = (__bf16)a.x; r[1] = (__bf16)a.y; r[2] = (__bf16)a.z; r[3] = (__bf16)a.w;
    r[4] = (__bf16)b.x; r[5] = (__bf16)b.y; r[6] = (__bf16)b.z; r[7] = (__bf16)b.w;
    return r;
}

// read 8 bf16 (16B) from LDS weight tile at (row, col off)
__device__ __forceinline__ bf16x8 ldsfrag_(const unsigned short* b, int row, int off) {
    union { bf16x8 v; uint4 u; } r;
    r.u = *(const uint4*)&b[row * WSTR + off];
    return r.v;
}

__device__ __forceinline__ bf16x8 pack_bf_(f32x4 lo, f32x4 hi) {
    bf16x8 r;
    r[0] = (__bf16)lo[0]; r[1] = (__bf16)lo[1]; r[2] = (__bf16)lo[2]; r[3] = (__bf16)lo[3];
    r[4] = (__bf16)hi[0]; r[5] = (__bf16)hi[1]; r[6] = (__bf16)hi[2]; r[7] = (__bf16)hi[3];
    return r;
}

// R17: 256-thread block = 4 waves, each wave runs TWO independent recurrence
// chains (2 x 16 sites) -> 128 sites/block, 782 blocks.
// R16 post-mortem: capacity has been pinned at 16 waves/CU across R12/R15/R16
// (VGPR bucket: 65..128 VGPR -> 4 waves/SIMD), dur pinned ~45us with
// VALU+MFMA issue only ~50% -- stall-dominated serial chains. Instead of
// fighting for more waves, double the independent work per wave: the big
// loop-invariant state (a_hh 32 + a_head 8 + biasD/wihD 32 + headC 4 VGPRs)
// is SHARED between chains; marginal cost per chain is bf (8) + transient acc.
// Chains are written back-to-back so transient accs don't peak together
// (peak ~124 VGPR, under the 128 bucket; launch_bounds(256,4) pins cap=128).
// Blocks halve to 782 -> 3.05 blocks/CU work vs 4 capacity -> one round.
//
// LDS overlay (R14/R15-validated): logits (20480B for 128 sites) overlay the
// dead 18432B weight region; __syncthreads() separates last cross-wave weight
// read from first logit write. LDS = 20480 + xs 9728 = 30208B (allows 5).
// Loop body per chain = validated R8/R10 permuted-output-row MFMA recurrence.
// Slot semantics: pL[sl*20+k] = p-logit(h_k) k=0..19;
//                 psiL[sl*20+k] = psi-logit(h_k) k=1..19, slot0 = psi0-logit.
__global__ __launch_bounds__(256, 4)
void rnet_kernel(const float* __restrict__ sxy0,
                 const float* __restrict__ sxy,
                 const float* __restrict__ oxy,
                 const float* __restrict__ W_h0, const float* __restrict__ b_h0,
                 const float* __restrict__ W_h1, const float* __restrict__ b_h1,
                 const float* __restrict__ W_ih, const float* __restrict__ b_ih,
                 const float* __restrict__ W_hh, const float* __restrict__ b_hh,
                 const float* __restrict__ W_psi0, const float* __restrict__ b_psi0,
                 const float* __restrict__ W_psi, const float* __restrict__ b_psi,
                 const float* __restrict__ W_p, const float* __restrict__ b_p,
                 float* __restrict__ out)
{
    const int tid  = threadIdx.x;       // 0..255
    const int lane = tid & 63;
    const int wv   = tid >> 6;          // wave 0..3
    const int s = lane & 15;            // site within chain / A-row within tile
    const int q = lane >> 4;            // quad
    const int sq = s >> 2, sr = s & 3;
    const int base = blockIdx.x * SPB;  // 782 blocks; last block partial
    const int slA  = wv * 16 + s;       // chain A site local 0..63
    const int slB  = slA + 64;          // chain B site local 64..127
    const int siteA = base + slA;
    const int siteB = base + slB;
    const int siteA_ld = siteA < NSITES ? siteA : NSITES - 1;
    const int siteB_ld = siteB < NSITES ? siteB : NSITES - 1;

    // ==== LDS: region = weights (18432B) overlaid later by logits (20480B) ====
    __shared__ __align__(16) unsigned char region[SPB * 20 * 2 * 4];  // 20480B
    __shared__ __align__(16) float xs_sh[SPB * 19];                   // 9728B
    unsigned short* const whh_l = (unsigned short*)region;            // bf16 W_hh [64][WSTR]
    unsigned short* const wh1_l = (unsigned short*)region + 64 * WSTR;// bf16 W_h1 [64][WSTR]
    float* const pL   = (float*)region;                 // [128][20] raw p logits (overlay)
    float* const psiL = (float*)region + SPB * 20;      // [128][20]; slot0 = psi0 logit

    float* __restrict__ out_psi0 = out;                 // [N]
    float* __restrict__ out_psi  = out + NSITES;        // [N,19]
    float* __restrict__ out_p    = out + 20 * NSITES;   // [N,20,2]

    // ==== stage weights (coalesced f32->bf16) + xs into LDS ====
    {
        const float4* whg = (const float4*)W_hh;
        const float4* w1g = (const float4*)W_h1;
#pragma unroll
        for (int j = 0; j < 4; ++j) {
            int e4 = j * 256 + tid;            // 0..1023 (1024 float4 = 64x64)
            int row = e4 >> 4, c4 = e4 & 15;
            float4 a = whg[e4];
            uint2 pa; pa.x = pack2_(a.x, a.y); pa.y = pack2_(a.z, a.w);
            *(uint2*)&whh_l[row * WSTR + c4 * 4] = pa;
            float4 b = w1g[e4];
            uint2 pb; pb.x = pack2_(b.x, b.y); pb.y = pack2_(b.z, b.w);
            *(uint2*)&wh1_l[row * WSTR + c4 * 4] = pb;
        }
        // xs: 128*19 = 2432 floats; clamp per-site row for tail block
#pragma unroll
        for (int r = 0; r < 10; ++r) {
            int i = r * 256 + tid;
            if (i < SPB * 19) {
                int srow = i / 19, c = i - srow * 19;
                int gsite = base + srow; if (gsite >= NSITES) gsite = NSITES - 1;
                xs_sh[i] = sxy[(size_t)gsite * 19 + c];
            }
        }
    }
    __syncthreads();

    // ==== h0 stage (both chains): hs = elu(s0*W_h0+b_h0); h0 via permuted W_h1 ====
    bf16x8 bfA[2], bfB[2];
    {
        const float s0A = sxy0[siteA_ld];
        const float s0B = sxy0[siteB_ld];
        bf16x8 b0A[2], b0B[2];
#pragma unroll
        for (int kt = 0; kt < 2; ++kt) {
            const float* wp = W_h0 + kt * 32 + q * 8;
            const float* bp = b_h0 + kt * 32 + q * 8;
            float4 w0 = ((const float4*)wp)[0], w1 = ((const float4*)wp)[1];
            float4 c0 = ((const float4*)bp)[0], c1 = ((const float4*)bp)[1];
            float vA[8], vB[8];
            vA[0] = eluf_(fmaf(s0A, w0.x, c0.x)); vA[1] = eluf_(fmaf(s0A, w0.y, c0.y));
            vA[2] = eluf_(fmaf(s0A, w0.z, c0.z)); vA[3] = eluf_(fmaf(s0A, w0.w, c0.w));
            vA[4] = eluf_(fmaf(s0A, w1.x, c1.x)); vA[5] = eluf_(fmaf(s0A, w1.y, c1.y));
            vA[6] = eluf_(fmaf(s0A, w1.z, c1.z)); vA[7] = eluf_(fmaf(s0A, w1.w, c1.w));
            vB[0] = eluf_(fmaf(s0B, w0.x, c0.x)); vB[1] = eluf_(fmaf(s0B, w0.y, c0.y));
            vB[2] = eluf_(fmaf(s0B, w0.z, c0.z)); vB[3] = eluf_(fmaf(s0B, w0.w, c0.w));
            vB[4] = eluf_(fmaf(s0B, w1.x, c1.x)); vB[5] = eluf_(fmaf(s0B, w1.y, c1.y));
            vB[6] = eluf_(fmaf(s0B, w1.z, c1.z)); vB[7] = eluf_(fmaf(s0B, w1.w, c1.w));
#pragma unroll
            for (int j = 0; j < 8; ++j) { b0A[kt][j] = (__bf16)vA[j]; b0B[kt][j] = (__bf16)vB[j]; }
        }

        f32x4 accA[4], accB[4];
#pragma unroll
        for (int mt = 0; mt < 4; ++mt) {
            const int dr = 32 * (mt >> 1) + 8 * q + 4 * (mt & 1);
            float4 b1 = *(const float4*)(b_h1 + dr);
            accA[mt][0] = b1.x; accA[mt][1] = b1.y; accA[mt][2] = b1.z; accA[mt][3] = b1.w;
            accB[mt] = accA[mt];
        }
#pragma unroll
        for (int kt = 0; kt < 2; ++kt)
#pragma unroll
            for (int mt = 0; mt < 4; ++mt) {
                const int ar = 32 * (mt >> 1) + 8 * sq + 4 * (mt & 1) + sr;
                bf16x8 a = ldsfrag_(wh1_l, ar, kt * 32 + q * 8);
                accA[mt] = __builtin_amdgcn_mfma_f32_16x16x32_bf16(a, b0A[kt], accA[mt], 0, 0, 0);
                accB[mt] = __builtin_amdgcn_mfma_f32_16x16x32_bf16(a, b0B[kt], accB[mt], 0, 0, 0);
            }
        f32x4 eA[4], eB[4];
#pragma unroll
        for (int mt = 0; mt < 4; ++mt)
#pragma unroll
            for (int r = 0; r < 4; ++r) { eA[mt][r] = eluf_(accA[mt][r]); eB[mt][r] = eluf_(accB[mt][r]); }
        bfA[0] = pack_bf_(eA[0], eA[1]);
        bfA[1] = pack_bf_(eA[2], eA[3]);
        bfB[0] = pack_bf_(eB[0], eB[1]);
        bfB[1] = pack_bf_(eB[2], eB[3]);
    }

    // ==== persistent loop state: a_hh from LDS, small stuff direct ====
    bf16x8 a_hh[4][2];
#pragma unroll
    for (int mt = 0; mt < 4; ++mt) {
        const int ar = 32 * (mt >> 1) + 8 * sq + 4 * (mt & 1) + sr;
#pragma unroll
        for (int kt = 0; kt < 2; ++kt)
            a_hh[mt][kt] = ldsfrag_(whh_l, ar, kt * 32 + q * 8);
    }

    // ALL cross-wave LDS weight reads are now done (wh1_l in h0 stage, whh_l
    // just above). Barrier before any wave overwrites the region with logits.
    __syncthreads();

    bf16x8 a_head[2];
    {
        const float* hrow = (s == 1) ? W_p : ((s == 2) ? W_psi0 : W_psi);
#pragma unroll
        for (int kt = 0; kt < 2; ++kt) a_head[kt] = cvt8_(hrow + kt * 32 + q * 8);
    }
    f32x4 biasD[4], wihD[4];
#pragma unroll
    for (int mt = 0; mt < 4; ++mt) {
        const int dr = 32 * (mt >> 1) + 8 * q + 4 * (mt & 1);
        float4 bi = *(const float4*)(b_ih + dr);
        float4 bh = *(const float4*)(b_hh + dr);
        float4 wi = *(const float4*)(W_ih + dr);
        biasD[mt][0] = bi.x + bh.x; biasD[mt][1] = bi.y + bh.y;
        biasD[mt][2] = bi.z + bh.z; biasD[mt][3] = bi.w + bh.w;
        wihD[mt][0] = wi.x; wihD[mt][1] = wi.y; wihD[mt][2] = wi.z; wihD[mt][3] = wi.w;
    }
    f32x4 headC;
    headC[0] = (q == 0) ? b_psi[0]  : 0.0f;
    headC[1] = (q == 0) ? b_p[0]    : 0.0f;
    headC[2] = (q == 0) ? b_psi0[0] : 0.0f;
    headC[3] = 0.0f;

    // ==== recurrence: ROLLED, two chains per wave, xs pipelined one round ====
    float xA = xs_sh[slA * 19];
    float xB = xs_sh[slB * 19];
#pragma unroll 1
    for (int t = 1; t < NYEARS; ++t) {
        float xAn = (t < NYEARS - 1) ? xs_sh[slA * 19 + t] : 0.0f;
        float xBn = (t < NYEARS - 1) ? xs_sh[slB * 19 + t] : 0.0f;

        // ---- chain A ----
        {
            f32x4 acc[4], accH;
#pragma unroll
            for (int mt = 0; mt < 4; ++mt)
                acc[mt] = __builtin_amdgcn_mfma_f32_16x16x32_bf16(a_hh[mt][0], bfA[0], biasD[mt], 0, 0, 0);
            accH = __builtin_amdgcn_mfma_f32_16x16x32_bf16(a_head[0], bfA[0], headC, 0, 0, 0);
#pragma unroll
            for (int mt = 0; mt < 4; ++mt)
                acc[mt] = __builtin_amdgcn_mfma_f32_16x16x32_bf16(a_hh[mt][1], bfA[1], acc[mt], 0, 0, 0);
            accH = __builtin_amdgcn_mfma_f32_16x16x32_bf16(a_head[1], bfA[1], accH, 0, 0, 0);
            f32x4 hn[4];
#pragma unroll
            for (int mt = 0; mt < 4; ++mt)
#pragma unroll
                for (int r = 0; r < 4; ++r)
                    hn[mt][r] = fmaxf(fmaf(xA, wihD[mt][r], acc[mt][r]), 0.0f);
            bfA[0] = pack_bf_(hn[0], hn[1]);
            bfA[1] = pack_bf_(hn[2], hn[3]);
            if (q == 0) {
                pL[slA * 20 + (t - 1)]   = accH[1];
                psiL[slA * 20 + (t - 1)] = accH[0];
                if (t == 1) psiL[slA * 20] = accH[2];
            }
        }
        // ---- chain B ----
        {
            f32x4 acc[4], accH;
#pragma unroll
            for (int mt = 0; mt < 4; ++mt)
                acc[mt] = __builtin_amdgcn_mfma_f32_16x16x32_bf16(a_hh[mt][0], bfB[0], biasD[mt], 0, 0, 0);
            accH = __builtin_amdgcn_mfma_f32_16x16x32_bf16(a_head[0], bfB[0], headC, 0, 0, 0);
#pragma unroll
            for (int mt = 0; mt < 4; ++mt)
                acc[mt] = __builtin_amdgcn_mfma_f32_16x16x32_bf16(a_hh[mt][1], bfB[1], acc[mt], 0, 0, 0);
            accH = __builtin_amdgcn_mfma_f32_16x16x32_bf16(a_head[1], bfB[1], accH, 0, 0, 0);
            f32x4 hn[4];
#pragma unroll
            for (int mt = 0; mt < 4; ++mt)
#pragma unroll
                for (int r = 0; r < 4; ++r)
                    hn[mt][r] = fmaxf(fmaf(xB, wihD[mt][r], acc[mt][r]), 0.0f);
            bfB[0] = pack_bf_(hn[0], hn[1]);
            bfB[1] = pack_bf_(hn[2], hn[3]);
            if (q == 0) {
                pL[slB * 20 + (t - 1)]   = accH[1];
                psiL[slB * 20 + (t - 1)] = accH[0];
                if (t == 1) psiL[slB * 20] = accH[2];
            }
        }
        xA = xAn; xB = xBn;
    }

    // ==== final heads on h_19 (both chains) ====
    {
        f32x4 accH = __builtin_amdgcn_mfma_f32_16x16x32_bf16(a_head[0], bfA[0], headC, 0, 0, 0);
        accH = __builtin_amdgcn_mfma_f32_16x16x32_bf16(a_head[1], bfA[1], accH, 0, 0, 0);
        if (q == 0) {
            pL[slA * 20 + 19]   = accH[1];
            psiL[slA * 20 + 19] = accH[0];
        }
    }
    {
        f32x4 accH = __builtin_amdgcn_mfma_f32_16x16x32_bf16(a_head[0], bfB[0], headC, 0, 0, 0);
        accH = __builtin_amdgcn_mfma_f32_16x16x32_bf16(a_head[1], bfB[1], accH, 0, 0, 0);
        if (q == 0) {
            pL[slB * 20 + 19]   = accH[1];
            psiL[slB * 20 + 19] = accH[0];
        }
    }

    __syncthreads();

    // ==== epilogue: sigmoid + oxy, 256 threads over 128 sites, guarded ====
    const float wpo = W_p[HDIM];
    if (tid < SPB && base + tid < NSITES) out_psi0[base + tid] = sigmoidf_(psiL[tid * 20]);
    // psi: 128*19 = 2432; out flat i = sl*19 + c <- psiL[sl*20 + c+1]
#pragma unroll
    for (int r = 0; r < 10; ++r) {
        int i = r * 256 + tid;
        if (i < SPB * 19 && (size_t)base * 19 + i < (size_t)NSITES * 19) {
            int s2 = i / 19, c = i - s2 * 19;
            out_psi[(size_t)base * 19 + i] = sigmoidf_(psiL[s2 * 20 + c + 1]);
        }
    }
    // p: 128*40 = 5120 floats = 1280 float4; float4 idx i4 -> logits pL[i4*2], pL[i4*2+1]
    const float4* oxy_b = (const float4*)(oxy + (size_t)base * 40);
    float4* outp_b = (float4*)(out_p + (size_t)base * 40);
    const int p4max = (NSITES * 40) / 4;   // global float4 bound
#pragma unroll
    for (int r = 0; r < 5; ++r) {
        int i4 = r * 256 + tid;
        if (i4 < SPB * 10 && blockIdx.x * (SPB * 10) + i4 < p4max) {
            float4 ox = oxy_b[i4];
            float lg0 = pL[i4 * 2];
            float lg1 = pL[i4 * 2 + 1];
            float4 pv;
            pv.x = sigmoidf_(fmaf(wpo, ox.x, lg0));
            pv.y = sigmoidf_(fmaf(wpo, ox.y, lg0));
            pv.z = sigmoidf_(fmaf(wpo, ox.z, lg1));
            pv.w = sigmoidf_(fmaf(wpo, ox.w, lg1));
            outp_b[i4] = pv;
        }
    }
}

extern "C" void kernel_launch(void* const* d_in, const int* in_sizes, int n_in,
                              void* d_out, int out_size, void* d_ws, size_t ws_size,
                              hipStream_t stream) {
    const float* sxy0   = (const float*)d_in[0];
    const float* sxy    = (const float*)d_in[1];
    const float* oxy    = (const float*)d_in[2];
    const float* W_h0   = (const float*)d_in[3];
    const float* b_h0   = (const float*)d_in[4];
    const float* W_h1   = (const float*)d_in[5];
    const float* b_h1   = (const float*)d_in[6];
    const float* W_ih   = (const float*)d_in[7];
    const float* b_ih   = (const float*)d_in[8];
    const float* W_hh   = (const float*)d_in[9];
    const float* b_hh   = (const float*)d_in[10];
    const float* W_psi0 = (const float*)d_in[11];
    const float* b_psi0 = (const float*)d_in[12];
    const float* W_psi  = (const float*)d_in[13];
    const float* b_psi  = (const float*)d_in[14];
    const float* W_p    = (const float*)d_in[15];
    const float* b_p    = (const float*)d_in[16];

    float* out = (float*)d_out;

    dim3 block(256);
    dim3 grid((NSITES + SPB - 1) / SPB);   // 782 blocks, 4 waves x 2 chains x 16 sites
    rnet_kernel<<<grid, block, 0, stream>>>(
        sxy0, sxy, oxy, W_h0, b_h0, W_h1, b_h1, W_ih, b_ih, W_hh, b_hh,
        W_psi0, b_psi0, W_psi, b_psi, W_p, b_p, out);
}

// Round 6
// 140.113 us; speedup vs baseline: 1.1751x; 1.1751x over previous
//
#include <hip/hip_runtime.h>
#include <math.h>

#define NSITES 100000
#define NYEARS 20
#define HDIM 64
#define WSTR 72   // LDS weight row stride (bf16 elems); 144B, 16B-aligned
#define SPB 128   // sites per block (4 waves x 2 chains x 16 sites)

typedef __bf16 bf16x8 __attribute__((ext_vector_type(8)));
typedef float f32x4 __attribute__((ext_vector_type(4)));

__device__ __forceinline__ float sigmoidf_(float x) { return 1.0f / (1.0f + __expf(-x)); }
// fast elu: __expf(x)-1 (error ~1e-7, far below tolerance; result is bf16-truncated anyway)
__device__ __forceinline__ float eluf_(float x) { return x > 0.0f ? x : __expf(x) - 1.0f; }

__device__ __forceinline__ unsigned pack2_(float a, float b) {
    union { __bf16 h; unsigned short u; } x, y;
    x.h = (__bf16)a; y.h = (__bf16)b;
    return ((unsigned)y.u << 16) | (unsigned)x.u;
}

// load 8 consecutive f32 (32B-aligned) -> bf16x8
__device__ __forceinline__ bf16x8 cvt8_(const float* p) {
    float4 a = ((const float4*)p)[0];
    float4 b = ((const float4*)p)[1];
    bf16x8 r;
    r[0] = (__bf16)a.x; r[1] = (__bf16)a.y; r[2] = (__bf16)a.z; r[3] = (__bf16)a.w;
    r[4] = (__bf16)b.x; r[5] = (__bf16)b.y; r[6] = (__bf16)b.z; r[7] = (__bf16)b.w;
    return r;
}

// read 8 bf16 (16B) from LDS weight tile at (row, col off)
__device__ __forceinline__ bf16x8 ldsfrag_(const unsigned short* b, int row, int off) {
    union { bf16x8 v; uint4 u; } r;
    r.u = *(const uint4*)&b[row * WSTR + off];
    return r.v;
}

__device__ __forceinline__ bf16x8 pack_bf_(f32x4 lo, f32x4 hi) {
    bf16x8 r;
    r[0] = (__bf16)lo[0]; r[1] = (__bf16)lo[1]; r[2] = (__bf16)lo[2]; r[3] = (__bf16)lo[3];
    r[4] = (__bf16)hi[0]; r[5] = (__bf16)hi[1]; r[6] = (__bf16)hi[2]; r[7] = (__bf16)hi[3];
    return r;
}

// R18: 256-thread block = 4 waves x 2 chains x 16 sites (128 sites/block,
// 782 blocks), launch_bounds(256,2).
// R17 post-mortem: the 2-chain idea was killed by launch_bounds(256,4) ->
// hipcc targeted a 64-VGPR budget and SPILLED the second chain (FETCH 12->33MB,
// WRITE 23->66MB, dur 73us). Every regression this session (R14, R17) was
// launch-bounds-induced spill, not the structure. Fix: (256,2) = cap 256,
// spill impossible (live state ~140). At ~140 VGPR -> 3 waves/SIMD -> 24
// chains/CU (same chain count as R15's 24 waves x 1 chain) but each wave now
// has 2 INDEPENDENT chains with MFMAs interleaved at instruction level:
// all 10 kt=0 MFMAs (A,B) issue back-to-back before any dependent kt=1 MFMA,
// covering MFMA latency; B's MFMA cluster runs under A's VALU tail. Attacks
// the ~50% dead issue slots that occupancy knobs (R12-R16) couldn't move.
//
// LDS overlay (R14/R15-validated): logits (20480B) overlay the dead 18432B
// weight region; __syncthreads() separates last cross-wave weight read from
// first logit write. LDS = 20480 + xs 9728 = 30208B.
// Loop body per chain = validated R8/R10 permuted-output-row MFMA recurrence.
// Slot semantics: pL[sl*20+k] = p-logit(h_k) k=0..19;
//                 psiL[sl*20+k] = psi-logit(h_k) k=1..19, slot0 = psi0-logit.
__global__ __launch_bounds__(256, 2)
void rnet_kernel(const float* __restrict__ sxy0,
                 const float* __restrict__ sxy,
                 const float* __restrict__ oxy,
                 const float* __restrict__ W_h0, const float* __restrict__ b_h0,
                 const float* __restrict__ W_h1, const float* __restrict__ b_h1,
                 const float* __restrict__ W_ih, const float* __restrict__ b_ih,
                 const float* __restrict__ W_hh, const float* __restrict__ b_hh,
                 const float* __restrict__ W_psi0, const float* __restrict__ b_psi0,
                 const float* __restrict__ W_psi, const float* __restrict__ b_psi,
                 const float* __restrict__ W_p, const float* __restrict__ b_p,
                 float* __restrict__ out)
{
    const int tid  = threadIdx.x;       // 0..255
    const int lane = tid & 63;
    const int wv   = tid >> 6;          // wave 0..3
    const int s = lane & 15;            // site within chain / A-row within tile
    const int q = lane >> 4;            // quad
    const int sq = s >> 2, sr = s & 3;
    const int base = blockIdx.x * SPB;  // 782 blocks; last block partial
    const int slA  = wv * 16 + s;       // chain A site local 0..63
    const int slB  = slA + 64;          // chain B site local 64..127
    const int siteA = base + slA;
    const int siteB = base + slB;
    const int siteA_ld = siteA < NSITES ? siteA : NSITES - 1;
    const int siteB_ld = siteB < NSITES ? siteB : NSITES - 1;

    // ==== LDS: region = weights (18432B) overlaid later by logits (20480B) ====
    __shared__ __align__(16) unsigned char region[SPB * 20 * 2 * 4];  // 20480B
    __shared__ __align__(16) float xs_sh[SPB * 19];                   // 9728B
    unsigned short* const whh_l = (unsigned short*)region;            // bf16 W_hh [64][WSTR]
    unsigned short* const wh1_l = (unsigned short*)region + 64 * WSTR;// bf16 W_h1 [64][WSTR]
    float* const pL   = (float*)region;                 // [128][20] raw p logits (overlay)
    float* const psiL = (float*)region + SPB * 20;      // [128][20]; slot0 = psi0 logit

    float* __restrict__ out_psi0 = out;                 // [N]
    float* __restrict__ out_psi  = out + NSITES;        // [N,19]
    float* __restrict__ out_p    = out + 20 * NSITES;   // [N,20,2]

    // ==== stage weights (coalesced f32->bf16) + xs into LDS ====
    {
        const float4* whg = (const float4*)W_hh;
        const float4* w1g = (const float4*)W_h1;
#pragma unroll
        for (int j = 0; j < 4; ++j) {
            int e4 = j * 256 + tid;            // 0..1023 (1024 float4 = 64x64)
            int row = e4 >> 4, c4 = e4 & 15;
            float4 a = whg[e4];
            uint2 pa; pa.x = pack2_(a.x, a.y); pa.y = pack2_(a.z, a.w);
            *(uint2*)&whh_l[row * WSTR + c4 * 4] = pa;
            float4 b = w1g[e4];
            uint2 pb; pb.x = pack2_(b.x, b.y); pb.y = pack2_(b.z, b.w);
            *(uint2*)&wh1_l[row * WSTR + c4 * 4] = pb;
        }
        // xs: 128*19 = 2432 floats; clamp per-site row for tail block
#pragma unroll
        for (int r = 0; r < 10; ++r) {
            int i = r * 256 + tid;
            if (i < SPB * 19) {
                int srow = i / 19, c = i - srow * 19;
                int gsite = base + srow; if (gsite >= NSITES) gsite = NSITES - 1;
                xs_sh[i] = sxy[(size_t)gsite * 19 + c];
            }
        }
    }
    __syncthreads();

    // ==== h0 stage (both chains): hs = elu(s0*W_h0+b_h0); h0 via permuted W_h1 ====
    bf16x8 bfA[2], bfB[2];
    {
        const float s0A = sxy0[siteA_ld];
        const float s0B = sxy0[siteB_ld];
        bf16x8 b0A[2], b0B[2];
#pragma unroll
        for (int kt = 0; kt < 2; ++kt) {
            const float* wp = W_h0 + kt * 32 + q * 8;
            const float* bp = b_h0 + kt * 32 + q * 8;
            float4 w0 = ((const float4*)wp)[0], w1 = ((const float4*)wp)[1];
            float4 c0 = ((const float4*)bp)[0], c1 = ((const float4*)bp)[1];
            float vA[8], vB[8];
            vA[0] = eluf_(fmaf(s0A, w0.x, c0.x)); vA[1] = eluf_(fmaf(s0A, w0.y, c0.y));
            vA[2] = eluf_(fmaf(s0A, w0.z, c0.z)); vA[3] = eluf_(fmaf(s0A, w0.w, c0.w));
            vA[4] = eluf_(fmaf(s0A, w1.x, c1.x)); vA[5] = eluf_(fmaf(s0A, w1.y, c1.y));
            vA[6] = eluf_(fmaf(s0A, w1.z, c1.z)); vA[7] = eluf_(fmaf(s0A, w1.w, c1.w));
            vB[0] = eluf_(fmaf(s0B, w0.x, c0.x)); vB[1] = eluf_(fmaf(s0B, w0.y, c0.y));
            vB[2] = eluf_(fmaf(s0B, w0.z, c0.z)); vB[3] = eluf_(fmaf(s0B, w0.w, c0.w));
            vB[4] = eluf_(fmaf(s0B, w1.x, c1.x)); vB[5] = eluf_(fmaf(s0B, w1.y, c1.y));
            vB[6] = eluf_(fmaf(s0B, w1.z, c1.z)); vB[7] = eluf_(fmaf(s0B, w1.w, c1.w));
#pragma unroll
            for (int j = 0; j < 8; ++j) { b0A[kt][j] = (__bf16)vA[j]; b0B[kt][j] = (__bf16)vB[j]; }
        }

        f32x4 accA[4], accB[4];
#pragma unroll
        for (int mt = 0; mt < 4; ++mt) {
            const int dr = 32 * (mt >> 1) + 8 * q + 4 * (mt & 1);
            float4 b1 = *(const float4*)(b_h1 + dr);
            accA[mt][0] = b1.x; accA[mt][1] = b1.y; accA[mt][2] = b1.z; accA[mt][3] = b1.w;
            accB[mt] = accA[mt];
        }
#pragma unroll
        for (int kt = 0; kt < 2; ++kt)
#pragma unroll
            for (int mt = 0; mt < 4; ++mt) {
                const int ar = 32 * (mt >> 1) + 8 * sq + 4 * (mt & 1) + sr;
                bf16x8 a = ldsfrag_(wh1_l, ar, kt * 32 + q * 8);
                accA[mt] = __builtin_amdgcn_mfma_f32_16x16x32_bf16(a, b0A[kt], accA[mt], 0, 0, 0);
                accB[mt] = __builtin_amdgcn_mfma_f32_16x16x32_bf16(a, b0B[kt], accB[mt], 0, 0, 0);
            }
        f32x4 eA[4], eB[4];
#pragma unroll
        for (int mt = 0; mt < 4; ++mt)
#pragma unroll
            for (int r = 0; r < 4; ++r) { eA[mt][r] = eluf_(accA[mt][r]); eB[mt][r] = eluf_(accB[mt][r]); }
        bfA[0] = pack_bf_(eA[0], eA[1]);
        bfA[1] = pack_bf_(eA[2], eA[3]);
        bfB[0] = pack_bf_(eB[0], eB[1]);
        bfB[1] = pack_bf_(eB[2], eB[3]);
    }

    // ==== persistent loop state: a_hh from LDS, small stuff direct ====
    bf16x8 a_hh[4][2];
#pragma unroll
    for (int mt = 0; mt < 4; ++mt) {
        const int ar = 32 * (mt >> 1) + 8 * sq + 4 * (mt & 1) + sr;
#pragma unroll
        for (int kt = 0; kt < 2; ++kt)
            a_hh[mt][kt] = ldsfrag_(whh_l, ar, kt * 32 + q * 8);
    }

    // ALL cross-wave LDS weight reads are now done (wh1_l in h0 stage, whh_l
    // just above). Barrier before any wave overwrites the region with logits.
    __syncthreads();

    bf16x8 a_head[2];
    {
        const float* hrow = (s == 1) ? W_p : ((s == 2) ? W_psi0 : W_psi);
#pragma unroll
        for (int kt = 0; kt < 2; ++kt) a_head[kt] = cvt8_(hrow + kt * 32 + q * 8);
    }
    f32x4 biasD[4], wihD[4];
#pragma unroll
    for (int mt = 0; mt < 4; ++mt) {
        const int dr = 32 * (mt >> 1) + 8 * q + 4 * (mt & 1);
        float4 bi = *(const float4*)(b_ih + dr);
        float4 bh = *(const float4*)(b_hh + dr);
        float4 wi = *(const float4*)(W_ih + dr);
        biasD[mt][0] = bi.x + bh.x; biasD[mt][1] = bi.y + bh.y;
        biasD[mt][2] = bi.z + bh.z; biasD[mt][3] = bi.w + bh.w;
        wihD[mt][0] = wi.x; wihD[mt][1] = wi.y; wihD[mt][2] = wi.z; wihD[mt][3] = wi.w;
    }
    f32x4 headC;
    headC[0] = (q == 0) ? b_psi[0]  : 0.0f;
    headC[1] = (q == 0) ? b_p[0]    : 0.0f;
    headC[2] = (q == 0) ? b_psi0[0] : 0.0f;
    headC[3] = 0.0f;

    // ==== recurrence: ROLLED, 2 chains interleaved at MFMA level ====
    float xA = xs_sh[slA * 19];
    float xB = xs_sh[slB * 19];
#pragma unroll 1
    for (int t = 1; t < NYEARS; ++t) {
        float xAn = (t < NYEARS - 1) ? xs_sh[slA * 19 + t] : 0.0f;
        float xBn = (t < NYEARS - 1) ? xs_sh[slB * 19 + t] : 0.0f;

        f32x4 accA[4], accB[4], accHA, accHB;
        // --- 10 independent kt=0 MFMAs (A then B) ---
#pragma unroll
        for (int mt = 0; mt < 4; ++mt)
            accA[mt] = __builtin_amdgcn_mfma_f32_16x16x32_bf16(a_hh[mt][0], bfA[0], biasD[mt], 0, 0, 0);
        accHA = __builtin_amdgcn_mfma_f32_16x16x32_bf16(a_head[0], bfA[0], headC, 0, 0, 0);
#pragma unroll
        for (int mt = 0; mt < 4; ++mt)
            accB[mt] = __builtin_amdgcn_mfma_f32_16x16x32_bf16(a_hh[mt][0], bfB[0], biasD[mt], 0, 0, 0);
        accHB = __builtin_amdgcn_mfma_f32_16x16x32_bf16(a_head[0], bfB[0], headC, 0, 0, 0);
        // --- dependent kt=1 MFMAs (A then B); A's kt=0 latency covered by B's kt=0 ---
#pragma unroll
        for (int mt = 0; mt < 4; ++mt)
            accA[mt] = __builtin_amdgcn_mfma_f32_16x16x32_bf16(a_hh[mt][1], bfA[1], accA[mt], 0, 0, 0);
        accHA = __builtin_amdgcn_mfma_f32_16x16x32_bf16(a_head[1], bfA[1], accHA, 0, 0, 0);
#pragma unroll
        for (int mt = 0; mt < 4; ++mt)
            accB[mt] = __builtin_amdgcn_mfma_f32_16x16x32_bf16(a_hh[mt][1], bfB[1], accB[mt], 0, 0, 0);
        accHB = __builtin_amdgcn_mfma_f32_16x16x32_bf16(a_head[1], bfB[1], accHB, 0, 0, 0);

        // --- VALU finish A (runs under B's MFMA latency), then B ---
        {
            f32x4 hn[4];
#pragma unroll
            for (int mt = 0; mt < 4; ++mt)
#pragma unroll
                for (int r = 0; r < 4; ++r)
                    hn[mt][r] = fmaxf(fmaf(xA, wihD[mt][r], accA[mt][r]), 0.0f);
            bfA[0] = pack_bf_(hn[0], hn[1]);
            bfA[1] = pack_bf_(hn[2], hn[3]);
            if (q == 0) {
                pL[slA * 20 + (t - 1)]   = accHA[1];
                psiL[slA * 20 + (t - 1)] = accHA[0];
                if (t == 1) psiL[slA * 20] = accHA[2];
            }
        }
        {
            f32x4 hn[4];
#pragma unroll
            for (int mt = 0; mt < 4; ++mt)
#pragma unroll
                for (int r = 0; r < 4; ++r)
                    hn[mt][r] = fmaxf(fmaf(xB, wihD[mt][r], accB[mt][r]), 0.0f);
            bfB[0] = pack_bf_(hn[0], hn[1]);
            bfB[1] = pack_bf_(hn[2], hn[3]);
            if (q == 0) {
                pL[slB * 20 + (t - 1)]   = accHB[1];
                psiL[slB * 20 + (t - 1)] = accHB[0];
                if (t == 1) psiL[slB * 20] = accHB[2];
            }
        }
        xA = xAn; xB = xBn;
    }

    // ==== final heads on h_19 (both chains, interleaved) ====
    {
        f32x4 accHA = __builtin_amdgcn_mfma_f32_16x16x32_bf16(a_head[0], bfA[0], headC, 0, 0, 0);
        f32x4 accHB = __builtin_amdgcn_mfma_f32_16x16x32_bf16(a_head[0], bfB[0], headC, 0, 0, 0);
        accHA = __builtin_amdgcn_mfma_f32_16x16x32_bf16(a_head[1], bfA[1], accHA, 0, 0, 0);
        accHB = __builtin_amdgcn_mfma_f32_16x16x32_bf16(a_head[1], bfB[1], accHB, 0, 0, 0);
        if (q == 0) {
            pL[slA * 20 + 19]   = accHA[1];
            psiL[slA * 20 + 19] = accHA[0];
            pL[slB * 20 + 19]   = accHB[1];
            psiL[slB * 20 + 19] = accHB[0];
        }
    }

    __syncthreads();

    // ==== epilogue: sigmoid + oxy, 256 threads over 128 sites, guarded ====
    const float wpo = W_p[HDIM];
    if (tid < SPB && base + tid < NSITES) out_psi0[base + tid] = sigmoidf_(psiL[tid * 20]);
    // psi: 128*19 = 2432; out flat i = sl*19 + c <- psiL[sl*20 + c+1]
#pragma unroll
    for (int r = 0; r < 10; ++r) {
        int i = r * 256 + tid;
        if (i < SPB * 19 && (size_t)base * 19 + i < (size_t)NSITES * 19) {
            int s2 = i / 19, c = i - s2 * 19;
            out_psi[(size_t)base * 19 + i] = sigmoidf_(psiL[s2 * 20 + c + 1]);
        }
    }
    // p: 128*40 = 5120 floats = 1280 float4; float4 idx i4 -> logits pL[i4*2], pL[i4*2+1]
    const float4* oxy_b = (const float4*)(oxy + (size_t)base * 40);
    float4* outp_b = (float4*)(out_p + (size_t)base * 40);
    const int p4max = (NSITES * 40) / 4;   // global float4 bound
#pragma unroll
    for (int r = 0; r < 5; ++r) {
        int i4 = r * 256 + tid;
        if (i4 < SPB * 10 && blockIdx.x * (SPB * 10) + i4 < p4max) {
            float4 ox = oxy_b[i4];
            float lg0 = pL[i4 * 2];
            float lg1 = pL[i4 * 2 + 1];
            float4 pv;
            pv.x = sigmoidf_(fmaf(wpo, ox.x, lg0));
            pv.y = sigmoidf_(fmaf(wpo, ox.y, lg0));
            pv.z = sigmoidf_(fmaf(wpo, ox.z, lg1));
            pv.w = sigmoidf_(fmaf(wpo, ox.w, lg1));
            outp_b[i4] = pv;
        }
    }
}

extern "C" void kernel_launch(void* const* d_in, const int* in_sizes, int n_in,
                              void* d_out, int out_size, void* d_ws, size_t ws_size,
                              hipStream_t stream) {
    const float* sxy0   = (const float*)d_in[0];
    const float* sxy    = (const float*)d_in[1];
    const float* oxy    = (const float*)d_in[2];
    const float* W_h0   = (const float*)d_in[3];
    const float* b_h0   = (const float*)d_in[4];
    const float* W_h1   = (const float*)d_in[5];
    const float* b_h1   = (const float*)d_in[6];
    const float* W_ih   = (const float*)d_in[7];
    const float* b_ih   = (const float*)d_in[8];
    const float* W_hh   = (const float*)d_in[9];
    const float* b_hh   = (const float*)d_in[10];
    const float* W_psi0 = (const float*)d_in[11];
    const float* b_psi0 = (const float*)d_in[12];
    const float* W_psi  = (const float*)d_in[13];
    const float* b_psi  = (const float*)d_in[14];
    const float* W_p    = (const float*)d_in[15];
    const float* b_p    = (const float*)d_in[16];

    float* out = (float*)d_out;

    dim3 block(256);
    dim3 grid((NSITES + SPB - 1) / SPB);   // 782 blocks, 4 waves x 2 chains x 16 sites
    rnet_kernel<<<grid, block, 0, stream>>>(
        sxy0, sxy, oxy, W_h0, b_h0, W_h1, b_h1, W_ih, b_ih, W_hh, b_hh,
        W_psi0, b_psi0, W_psi, b_psi, W_p, b_p, out);
}

// Round 8
// 136.006 us; speedup vs baseline: 1.2106x; 1.0302x over previous
//
#include <hip/hip_runtime.h>
#include <math.h>

#define NSITES 100000
#define NYEARS 20
#define HDIM 64
#define WSTR 72   // LDS weight row stride (f16 elems); 144B, 16B-aligned

typedef _Float16 f16x8 __attribute__((ext_vector_type(8)));
typedef _Float16 hx2   __attribute__((ext_vector_type(2)));
typedef float f32x4 __attribute__((ext_vector_type(4)));

__device__ __forceinline__ float sigmoidf_(float x) { return 1.0f / (1.0f + __expf(-x)); }
// fast elu: __expf(x)-1 (error ~1e-7, far below tolerance; result is f16-truncated anyway)
__device__ __forceinline__ float eluf_(float x) { return x > 0.0f ? x : __expf(x) - 1.0f; }

__device__ __forceinline__ unsigned pack2h_(float a, float b) {
    union { _Float16 h; unsigned short u; } x, y;
    x.h = (_Float16)a; y.h = (_Float16)b;
    return ((unsigned)y.u << 16) | (unsigned)x.u;
}

// load 8 consecutive f32 (32B-aligned) -> f16x8
__device__ __forceinline__ f16x8 cvt8h_(const float* p) {
    float4 a = ((const float4*)p)[0];
    float4 b = ((const float4*)p)[1];
    f16x8 r;
    r[0] = (_Float16)a.x; r[1] = (_Float16)a.y; r[2] = (_Float16)a.z; r[3] = (_Float16)a.w;
    r[4] = (_Float16)b.x; r[5] = (_Float16)b.y; r[6] = (_Float16)b.z; r[7] = (_Float16)b.w;
    return r;
}

// read 8 f16 (16B) from LDS weight tile at (row, col off)
__device__ __forceinline__ f16x8 ldsfrag_(const unsigned short* b, int row, int off) {
    union { f16x8 v; uint4 u; } r;
    r.u = *(const uint4*)&b[row * WSTR + off];
    return r.v;
}

union FragU { hx2 h2[4]; f16x8 v; };

// R20 = R19 with the packed-f16 math expressed in native clang _Float16
// vectors (ROCm 7.2 has no __hmax2 -- R19 was a pure compile failure; the
// theory is untested until now).
// Structure (R15-validated 1-chain, 4 waves x 16 sites, 64 sites/block,
// 1563 blocks, launch_bounds(256,2) -- the only binding that never spilled):
//  1. LDS 23552 -> 18432 B: xs_sh ELIMINATED -- x read from global in the
//     t-loop, pipelined one iteration ahead (sxy = 7.6MB, L2-resident).
//     Logits (10240B) overlay the dead weight region (R14/R15-validated).
//     Raises blocks/CU under ANY LDS-pool hypothesis (dur=45us invariant
//     across R12/R15/R16/R18 at 23-34KB/block points at residency).
//  2. bf16 -> f16 (mfma_f32_16x16x32_f16, same rate, 10-bit mantissa):
//     relu update in packed f16: cvt + pk_fma + pk_max = ~6 ops vs 14
//     scalar per mt. Loop VALU 56 -> ~26 ops/thread/iter; wih 16 -> 8 VGPR.
// Loop body = validated R8/R10 permuted-output-row MFMA recurrence (lane's D
// regs ARE its next-round B-fragment), heads as 5th m-tile.
// Slot semantics: pL[sl*20+k] = p-logit(h_k) k=0..19;
//                 psiL[sl*20+k] = psi-logit(h_k) k=1..19, slot0 = psi0-logit.
__global__ __launch_bounds__(256, 2)
void rnet_kernel(const float* __restrict__ sxy0,
                 const float* __restrict__ sxy,
                 const float* __restrict__ oxy,
                 const float* __restrict__ W_h0, const float* __restrict__ b_h0,
                 const float* __restrict__ W_h1, const float* __restrict__ b_h1,
                 const float* __restrict__ W_ih, const float* __restrict__ b_ih,
                 const float* __restrict__ W_hh, const float* __restrict__ b_hh,
                 const float* __restrict__ W_psi0, const float* __restrict__ b_psi0,
                 const float* __restrict__ W_psi, const float* __restrict__ b_psi,
                 const float* __restrict__ W_p, const float* __restrict__ b_p,
                 float* __restrict__ out)
{
    const int tid  = threadIdx.x;       // 0..255
    const int lane = tid & 63;
    const int wv   = tid >> 6;          // wave 0..3
    const int s = lane & 15;            // site within wave / A-row within tile
    const int q = lane >> 4;            // quad
    const int sq = s >> 2, sr = s & 3;
    const int base = blockIdx.x * 64;   // 1563 blocks; last block partial
    const int sl   = wv * 16 + s;       // site local 0..63
    const int site = base + sl;
    const int site_ld = site < NSITES ? site : NSITES - 1;   // clamped for loads

    // ==== LDS: single 18432B region = weights, later overlaid by logits ====
    __shared__ __align__(16) unsigned short wbuf[2 * 64 * WSTR]; // 18432 B
    unsigned short* const whh_l = wbuf;                 // f16 W_hh [64][WSTR]
    unsigned short* const wh1_l = wbuf + 64 * WSTR;     // f16 W_h1 [64][WSTR]
    float* const pL   = (float*)wbuf;                   // [64][20] p logits (overlay)
    float* const psiL = (float*)wbuf + 64 * 20;         // [64][20]; slot0 = psi0 logit

    float* __restrict__ out_psi0 = out;                 // [N]
    float* __restrict__ out_psi  = out + NSITES;        // [N,19]
    float* __restrict__ out_p    = out + 20 * NSITES;   // [N,20,2]

    // ==== stage weights (coalesced f32->f16) into LDS ====
    {
        const float4* whg = (const float4*)W_hh;
        const float4* w1g = (const float4*)W_h1;
#pragma unroll
        for (int j = 0; j < 4; ++j) {
            int e4 = j * 256 + tid;            // 0..1023 (1024 float4 = 64x64)
            int row = e4 >> 4, c4 = e4 & 15;
            float4 a = whg[e4];
            uint2 pa; pa.x = pack2h_(a.x, a.y); pa.y = pack2h_(a.z, a.w);
            *(uint2*)&whh_l[row * WSTR + c4 * 4] = pa;
            float4 b = w1g[e4];
            uint2 pb; pb.x = pack2h_(b.x, b.y); pb.y = pack2h_(b.z, b.w);
            *(uint2*)&wh1_l[row * WSTR + c4 * 4] = pb;
        }
    }
    __syncthreads();

    // ==== h0 stage: hs = elu(s0*W_h0+b_h0) in B layout; h0 via permuted W_h1 ====
    f16x8 bf[2];
    {
        const float s0v = sxy0[site_ld];
        f16x8 bf0[2];
#pragma unroll
        for (int kt = 0; kt < 2; ++kt) {
            const float* wp = W_h0 + kt * 32 + q * 8;
            const float* bp = b_h0 + kt * 32 + q * 8;
            float4 w0 = ((const float4*)wp)[0], w1 = ((const float4*)wp)[1];
            float4 c0 = ((const float4*)bp)[0], c1 = ((const float4*)bp)[1];
            float v[8];
            v[0] = eluf_(fmaf(s0v, w0.x, c0.x)); v[1] = eluf_(fmaf(s0v, w0.y, c0.y));
            v[2] = eluf_(fmaf(s0v, w0.z, c0.z)); v[3] = eluf_(fmaf(s0v, w0.w, c0.w));
            v[4] = eluf_(fmaf(s0v, w1.x, c1.x)); v[5] = eluf_(fmaf(s0v, w1.y, c1.y));
            v[6] = eluf_(fmaf(s0v, w1.z, c1.z)); v[7] = eluf_(fmaf(s0v, w1.w, c1.w));
#pragma unroll
            for (int j = 0; j < 8; ++j) bf0[kt][j] = (_Float16)v[j];
        }

        f32x4 acc[4];
#pragma unroll
        for (int mt = 0; mt < 4; ++mt) {
            const int dr = 32 * (mt >> 1) + 8 * q + 4 * (mt & 1);
            float4 b1 = *(const float4*)(b_h1 + dr);
            acc[mt][0] = b1.x; acc[mt][1] = b1.y; acc[mt][2] = b1.z; acc[mt][3] = b1.w;
        }
#pragma unroll
        for (int kt = 0; kt < 2; ++kt)
#pragma unroll
            for (int mt = 0; mt < 4; ++mt) {
                const int ar = 32 * (mt >> 1) + 8 * sq + 4 * (mt & 1) + sr;
                f16x8 a = ldsfrag_(wh1_l, ar, kt * 32 + q * 8);
                acc[mt] = __builtin_amdgcn_mfma_f32_16x16x32_f16(a, bf0[kt], acc[mt], 0, 0, 0);
            }
        FragU f0, f1;
#pragma unroll
        for (int mt = 0; mt < 4; ++mt) {
            hx2 plo; plo[0] = (_Float16)eluf_(acc[mt][0]); plo[1] = (_Float16)eluf_(acc[mt][1]);
            hx2 phi; phi[0] = (_Float16)eluf_(acc[mt][2]); phi[1] = (_Float16)eluf_(acc[mt][3]);
            if (mt < 2) { f0.h2[mt * 2] = plo; f0.h2[mt * 2 + 1] = phi; }
            else        { f1.h2[(mt - 2) * 2] = plo; f1.h2[(mt - 2) * 2 + 1] = phi; }
        }
        bf[0] = f0.v;
        bf[1] = f1.v;
    }

    // ==== persistent loop state: a_hh from LDS, small stuff direct ====
    f16x8 a_hh[4][2];
#pragma unroll
    for (int mt = 0; mt < 4; ++mt) {
        const int ar = 32 * (mt >> 1) + 8 * sq + 4 * (mt & 1) + sr;
#pragma unroll
        for (int kt = 0; kt < 2; ++kt)
            a_hh[mt][kt] = ldsfrag_(whh_l, ar, kt * 32 + q * 8);
    }

    // ALL cross-wave LDS weight reads done (wh1_l in h0, whh_l above).
    // Barrier before any wave overwrites the region with logits.
    __syncthreads();

    f16x8 a_head[2];
    {
        const float* hrow = (s == 1) ? W_p : ((s == 2) ? W_psi0 : W_psi);
#pragma unroll
        for (int kt = 0; kt < 2; ++kt) a_head[kt] = cvt8h_(hrow + kt * 32 + q * 8);
    }
    f32x4 biasD[4];
    hx2 wih2[4][2];
#pragma unroll
    for (int mt = 0; mt < 4; ++mt) {
        const int dr = 32 * (mt >> 1) + 8 * q + 4 * (mt & 1);
        float4 bi = *(const float4*)(b_ih + dr);
        float4 bh = *(const float4*)(b_hh + dr);
        float4 wi = *(const float4*)(W_ih + dr);
        biasD[mt][0] = bi.x + bh.x; biasD[mt][1] = bi.y + bh.y;
        biasD[mt][2] = bi.z + bh.z; biasD[mt][3] = bi.w + bh.w;
        wih2[mt][0][0] = (_Float16)wi.x; wih2[mt][0][1] = (_Float16)wi.y;
        wih2[mt][1][0] = (_Float16)wi.z; wih2[mt][1][1] = (_Float16)wi.w;
    }
    f32x4 headC;
    headC[0] = (q == 0) ? b_psi[0]  : 0.0f;
    headC[1] = (q == 0) ? b_p[0]    : 0.0f;
    headC[2] = (q == 0) ? b_psi0[0] : 0.0f;
    headC[3] = 0.0f;
    const hx2 z2 = (hx2)(_Float16)0.0f;
    const float* __restrict__ xs_g = sxy + (size_t)site_ld * 19;

    // ==== recurrence: ROLLED, x read from GLOBAL pipelined one round ahead ====
    float x = xs_g[0];                 // x for round t=1
#pragma unroll 1
    for (int t = 1; t < NYEARS; ++t) {
        float x_next = (t < NYEARS - 1) ? xs_g[t] : 0.0f;

        f32x4 acc[4], accH;
#pragma unroll
        for (int mt = 0; mt < 4; ++mt)
            acc[mt] = __builtin_amdgcn_mfma_f32_16x16x32_f16(a_hh[mt][0], bf[0], biasD[mt], 0, 0, 0);
        accH = __builtin_amdgcn_mfma_f32_16x16x32_f16(a_head[0], bf[0], headC, 0, 0, 0);
#pragma unroll
        for (int mt = 0; mt < 4; ++mt)
            acc[mt] = __builtin_amdgcn_mfma_f32_16x16x32_f16(a_hh[mt][1], bf[1], acc[mt], 0, 0, 0);
        accH = __builtin_amdgcn_mfma_f32_16x16x32_f16(a_head[1], bf[1], accH, 0, 0, 0);

        // packed-f16 relu update: hn = max(acc + x*wih, 0); result IS B-frag
        _Float16 xh = (_Float16)x;
        hx2 x2; x2[0] = xh; x2[1] = xh;
        FragU f0, f1;
#pragma unroll
        for (int mt = 0; mt < 4; ++mt) {
            hx2 plo; plo[0] = (_Float16)acc[mt][0]; plo[1] = (_Float16)acc[mt][1];
            hx2 phi; phi[0] = (_Float16)acc[mt][2]; phi[1] = (_Float16)acc[mt][3];
            plo = __builtin_elementwise_max(plo + x2 * wih2[mt][0], z2);
            phi = __builtin_elementwise_max(phi + x2 * wih2[mt][1], z2);
            if (mt < 2) { f0.h2[mt * 2] = plo; f0.h2[mt * 2 + 1] = phi; }
            else        { f1.h2[(mt - 2) * 2] = plo; f1.h2[(mt - 2) * 2 + 1] = phi; }
        }
        bf[0] = f0.v;
        bf[1] = f1.v;

        if (q == 0) {
            // accH is from bf = h_{t-1}: slot (t-1) semantics (R12-validated).
            pL[sl * 20 + (t - 1)]   = accH[1];   // p-logit(h_{t-1}), slots 0..18
            psiL[sl * 20 + (t - 1)] = accH[0];   // psi-logit(h_{t-1}); slot 0 dead
            if (t == 1) psiL[sl * 20] = accH[2]; // overwrite dead slot 0 w/ psi0
        }
        x = x_next;
    }

    // ==== final heads on h_19 ====
    {
        f32x4 accH = __builtin_amdgcn_mfma_f32_16x16x32_f16(a_head[0], bf[0], headC, 0, 0, 0);
        accH = __builtin_amdgcn_mfma_f32_16x16x32_f16(a_head[1], bf[1], accH, 0, 0, 0);
        if (q == 0) {
            pL[sl * 20 + 19]   = accH[1];   // p-logit(h_19)
            psiL[sl * 20 + 19] = accH[0];   // psi-logit(h_19)
        }
    }

    __syncthreads();

    // ==== epilogue: sigmoid + oxy, 256 threads over 64 sites, guarded ====
    const float wpo = W_p[HDIM];
    if (tid < 64 && base + tid < NSITES) out_psi0[base + tid] = sigmoidf_(psiL[tid * 20]);
    // psi: 64*19 = 1216; out flat i = sl*19 + c <- psiL[sl*20 + c+1]
#pragma unroll
    for (int r = 0; r < 5; ++r) {
        int i = r * 256 + tid;
        if (i < 64 * 19 && (size_t)base * 19 + i < (size_t)NSITES * 19) {
            int s2 = i / 19, c = i - s2 * 19;
            out_psi[(size_t)base * 19 + i] = sigmoidf_(psiL[s2 * 20 + c + 1]);
        }
    }
    // p: 64*40 = 2560 floats = 640 float4; float4 idx i4 -> logits pL[i4*2..+1]
    const float4* oxy_b = (const float4*)(oxy + (size_t)base * 40);
    float4* outp_b = (float4*)(out_p + (size_t)base * 40);
    const int p4max = (NSITES * 40) / 4;   // global float4 bound
#pragma unroll
    for (int r = 0; r < 3; ++r) {
        int i4 = r * 256 + tid;
        if (i4 < 640 && blockIdx.x * 640 + i4 < p4max) {
            float4 ox = oxy_b[i4];
            float lg0 = pL[i4 * 2];
            float lg1 = pL[i4 * 2 + 1];
            float4 pv;
            pv.x = sigmoidf_(fmaf(wpo, ox.x, lg0));
            pv.y = sigmoidf_(fmaf(wpo, ox.y, lg0));
            pv.z = sigmoidf_(fmaf(wpo, ox.z, lg1));
            pv.w = sigmoidf_(fmaf(wpo, ox.w, lg1));
            outp_b[i4] = pv;
        }
    }
}

extern "C" void kernel_launch(void* const* d_in, const int* in_sizes, int n_in,
                              void* d_out, int out_size, void* d_ws, size_t ws_size,
                              hipStream_t stream) {
    const float* sxy0   = (const float*)d_in[0];
    const float* sxy    = (const float*)d_in[1];
    const float* oxy    = (const float*)d_in[2];
    const float* W_h0   = (const float*)d_in[3];
    const float* b_h0   = (const float*)d_in[4];
    const float* W_h1   = (const float*)d_in[5];
    const float* b_h1   = (const float*)d_in[6];
    const float* W_ih   = (const float*)d_in[7];
    const float* b_ih   = (const float*)d_in[8];
    const float* W_hh   = (const float*)d_in[9];
    const float* b_hh   = (const float*)d_in[10];
    const float* W_psi0 = (const float*)d_in[11];
    const float* b_psi0 = (const float*)d_in[12];
    const float* W_psi  = (const float*)d_in[13];
    const float* b_psi  = (const float*)d_in[14];
    const float* W_p    = (const float*)d_in[15];
    const float* b_p    = (const float*)d_in[16];

    float* out = (float*)d_out;

    dim3 block(256);
    dim3 grid((NSITES + 63) / 64);   // 1563 blocks, 4 waves x 16 sites each
    rnet_kernel<<<grid, block, 0, stream>>>(
        sxy0, sxy, oxy, W_h0, b_h0, W_h1, b_h1, W_ih, b_ih, W_hh, b_hh,
        W_psi0, b_psi0, W_psi, b_psi, W_p, b_p, out);
}